// Round 5
// baseline (76.237 us; speedup 1.0000x reference)
//
#include <hip/hip_runtime.h>

// VOCAB=1e6, DIM=64, BAGS=16384, N_IDX=819200, CAT_DIM=128.
// Output row = [eb(64) | eb(64) | cat(128)] = 256 f32.
//
// R5: quad-row gathers. Lane layout: g=lane>>4 (row of quad), sub=lane&15
// (16B slot). One global_load_dwordx4 fetches 4 full 256B rows (1KB) -> 4x
// fewer gather instructions than R4 for the same bytes (tests the
// instruction-rate-bound hypothesis). Flush stays wave-coalesced: shfl_xor
// reduce across the 4 row-classes, lane->dim remap, two 256B atomics.
// CHUNK=64: 819200 = 12800 waves x 64, 3200 blocks.

constexpr int CHUNK = 64;

__global__ __launch_bounds__(256) void init_out_kernel(
    const float* __restrict__ cat, float* __restrict__ out, int total)
{
    int t = blockIdx.x * 256 + threadIdx.x;   // total = num_bags*256
    if (t >= total) return;
    int b = t >> 8, c = t & 255;
    out[t] = (c < 128) ? 0.0f : cat[(b << 7) + (c - 128)];
}

__global__ __launch_bounds__(256) void embag_kernel(
    const int* __restrict__ wq,             // [VOCAB, 64] int32 codes
    const float* __restrict__ scales,       // [VOCAB]
    const float* __restrict__ biases,       // [VOCAB]
    const unsigned int* __restrict__ idx32, // indices viewed as u32 words
    const unsigned int* __restrict__ off32, // offsets viewed as u32 words
    float* __restrict__ out,                // [BAGS, 256]
    int num_bags, int n_idx)
{
    // int64 vs int32 layout detection (LE): high words of first indices == 0.
    const bool is64 = ((idx32[1] | idx32[3] | idx32[5] | idx32[7]) == 0u);
    const int sh = is64 ? 1 : 0;

    const int lane = threadIdx.x & 63;
    const int wid  = blockIdx.x * 4 + (threadIdx.x >> 6);
    const long long base = (long long)wid * CHUNK;
    if (base >= n_idx) return;
    const int i0  = (int)base;
    const int cnt = min(CHUNK, n_idx - i0);

    const int g   = lane >> 4;   // row-in-quad this lane handles
    const int sub = lane & 15;   // 16B slot within the row

    // Per-lane prefetch of idx/scale/bias for local row `lane`.
    const int li = i0 + min(lane, cnt - 1);
    const int myidx = (int)idx32[(unsigned)li << sh];
    const float mys = scales[myidx];
    const float myb = biases[myidx];

    // Row index for each of my 16 quad-loads (local row 4k+g).
    int ridx[16];
    #pragma unroll
    for (int k = 0; k < 16; ++k)
        ridx[k] = __shfl(myidx, 4 * k + g, 64);

    // Start bag: smallest b with off[b+1] > i0 (searchsorted-right semantics).
    int lo = 0, hi = num_bags - 1;
    while (lo < hi) {
        int mid = (lo + hi) >> 1;
        if ((int)off32[(unsigned)(mid + 1) << sh] > i0) hi = mid; else lo = mid + 1;
    }
    int b = lo;
    int bend = (int)off32[(unsigned)(b + 1) << sh];

    float a0 = 0.f, a1 = 0.f, a2 = 0.f, a3 = 0.f, ab = 0.f;

    auto flushbag = [&](int bag) {
        float v0 = a0, v1 = a1, v2 = a2, v3 = a3, vb = ab;
        // Reduce across the 4 row-classes (g encoded in lane bits 4..5).
        v0 += __shfl_xor(v0, 16, 64); v1 += __shfl_xor(v1, 16, 64);
        v2 += __shfl_xor(v2, 16, 64); v3 += __shfl_xor(v3, 16, 64);
        vb += __shfl_xor(vb, 16, 64);
        v0 += __shfl_xor(v0, 32, 64); v1 += __shfl_xor(v1, 32, 64);
        v2 += __shfl_xor(v2, 32, 64); v3 += __shfl_xor(v3, 32, 64);
        vb += __shfl_xor(vb, 32, 64);
        float w = (g == 0) ? v0 : (g == 1) ? v1 : (g == 2) ? v2 : v3;
        w += vb;
        // Lane -> dim remap: dim = sub*4 + g (64 unique dims, one 256B segment).
        float* p = out + ((long long)bag << 8) + (sub << 2) + g;
        atomicAdd(p, w);        // eb1
        atomicAdd(p + 64, w);   // eb2 (identical sum)
    };

    // Burst: 16 independent 1KB quad-gathers (4 rows per instruction).
    int4 q[16];
    #pragma unroll
    for (int k = 0; k < 16; ++k)
        q[k] = *(const int4*)((const char*)wq +
               ((long long)(unsigned)ridx[k] << 8) + (sub << 4));

    #pragma unroll
    for (int k = 0; k < 16; ++k) {
        if (4 * k >= cnt) break;
        const int jq = i0 + 4 * k;
        const int4 qq = q[k];
        if (jq + 3 < bend && 4 * k + 3 < cnt) {
            // Fast path: whole quad inside the current bag.
            const float s  = __shfl(mys, 4 * k + g, 64);
            const float bi = __shfl(myb, 4 * k + g, 64);
            a0 = fmaf((float)qq.x, s, a0);
            a1 = fmaf((float)qq.y, s, a1);
            a2 = fmaf((float)qq.z, s, a2);
            a3 = fmaf((float)qq.w, s, a3);
            ab += bi;
        } else {
            // Slow path: bag boundary (and/or tail) inside the quad.
            #pragma unroll
            for (int rr = 0; rr < 4; ++rr) {
                if (4 * k + rr >= cnt) break;
                const int j = jq + rr;
                while (j >= bend) {              // wave-uniform
                    flushbag(b);
                    a0 = a1 = a2 = a3 = ab = 0.f;
                    do { ++b; bend = (int)off32[(unsigned)(b + 1) << sh]; }
                    while (bend <= j);
                }
                const float s  = __shfl(mys, 4 * k + rr, 64);
                const float bi = __shfl(myb, 4 * k + rr, 64);
                if (g == rr) {                   // owning lanes only
                    a0 = fmaf((float)qq.x, s, a0);
                    a1 = fmaf((float)qq.y, s, a1);
                    a2 = fmaf((float)qq.z, s, a2);
                    a3 = fmaf((float)qq.w, s, a3);
                    ab += bi;
                }
            }
        }
    }
    flushbag(b);
}

extern "C" void kernel_launch(void* const* d_in, const int* in_sizes, int n_in,
                              void* d_out, int out_size, void* d_ws, size_t ws_size,
                              hipStream_t stream) {
    const int*          wq     = (const int*)d_in[0];
    const float*        scales = (const float*)d_in[1];
    const float*        biases = (const float*)d_in[2];
    const unsigned int* idx32  = (const unsigned int*)d_in[3];
    const unsigned int* off32  = (const unsigned int*)d_in[4];
    const float*        cat    = (const float*)d_in[5];
    float*              out    = (float*)d_out;

    const int num_bags = in_sizes[5] / 128;       // 16384
    const int n_idx    = in_sizes[3];             // 819200

    const int total = num_bags * 256;
    init_out_kernel<<<(total + 255) / 256, 256, 0, stream>>>(cat, out, total);

    const int nchunks = (n_idx + CHUNK - 1) / CHUNK;   // 12800 waves
    const int blocks  = (nchunks + 3) / 4;             // 3200
    embag_kernel<<<blocks, 256, 0, stream>>>(
        wq, scales, biases, idx32, off32, out, num_bags, n_idx);
}